// Round 1
// baseline (198.067 us; speedup 1.0000x reference)
//
#include <hip/hip_runtime.h>
#include <hip/hip_bf16.h>
#include <cmath>
#include <cstdint>

#define H_ 8
#define B_ 2
#define L_ 2048
#define D_ 512
#define M_ 4096   // B_*L_

typedef __attribute__((ext_vector_type(8))) short short8_t;
typedef __attribute__((ext_vector_type(4))) float float4_t;
typedef __attribute__((ext_vector_type(4))) unsigned short ushort4_t;

__device__ __forceinline__ unsigned short f2bf(float f) {
  union { float f; unsigned u; } v; v.f = f;
  unsigned r = v.u + 0x7fffu + ((v.u >> 16) & 1u);
  return (unsigned short)(r >> 16);
}

// ---------------------------------------------------------------- mask dtype
// bool mask: 1 byte/elem (random 0/1 bytes everywhere).
// int32 mask: 4 bytes/elem, bytes at i%4!=0 are always 0 for values {0,1}.
__global__ void detect_mask(const unsigned char* __restrict__ mask, int* __restrict__ flag) {
  int i0 = threadIdx.x * 16;
  int f = 0;
  for (int j = 0; j < 16; j++) {
    int idx = i0 + j;
    if ((idx & 3) && mask[idx]) f = 1;
  }
  unsigned long long any = __ballot(f);
  if (threadIdx.x == 0) *flag = any ? 1 : 0;   // 1 => bool (stride 1), 0 => int32 (stride 4)
}

// ---------------------------------------------------------------- f32 -> bf16
__global__ void cvt_kernel(const float* __restrict__ q, const float* __restrict__ k,
                           const float* __restrict__ v, const float* __restrict__ wq,
                           const float* __restrict__ wk, const float* __restrict__ wv,
                           const float* __restrict__ wfc,
                           unsigned short* __restrict__ qb, unsigned short* __restrict__ kb,
                           unsigned short* __restrict__ vb, unsigned short* __restrict__ wqb,
                           unsigned short* __restrict__ wkb, unsigned short* __restrict__ wvb,
                           unsigned short* __restrict__ wfcb) {
  int i = (blockIdx.x * 256 + threadIdx.x) * 4;
  if (i < M_ * D_) {
    float4_t a;
    ushort4_t o;
    a = *(const float4_t*)(q + i);
    o[0] = f2bf(a[0]); o[1] = f2bf(a[1]); o[2] = f2bf(a[2]); o[3] = f2bf(a[3]);
    *(ushort4_t*)(qb + i) = o;
    a = *(const float4_t*)(k + i);
    o[0] = f2bf(a[0]); o[1] = f2bf(a[1]); o[2] = f2bf(a[2]); o[3] = f2bf(a[3]);
    *(ushort4_t*)(kb + i) = o;
    a = *(const float4_t*)(v + i);
    o[0] = f2bf(a[0]); o[1] = f2bf(a[1]); o[2] = f2bf(a[2]); o[3] = f2bf(a[3]);
    *(ushort4_t*)(vb + i) = o;
  }
  if (i < 512 * 512) {
    float4_t a;
    ushort4_t o;
    a = *(const float4_t*)(wq + i);
    o[0] = f2bf(a[0]); o[1] = f2bf(a[1]); o[2] = f2bf(a[2]); o[3] = f2bf(a[3]);
    *(ushort4_t*)(wqb + i) = o;
    a = *(const float4_t*)(wk + i);
    o[0] = f2bf(a[0]); o[1] = f2bf(a[1]); o[2] = f2bf(a[2]); o[3] = f2bf(a[3]);
    *(ushort4_t*)(wkb + i) = o;
    a = *(const float4_t*)(wv + i);
    o[0] = f2bf(a[0]); o[1] = f2bf(a[1]); o[2] = f2bf(a[2]); o[3] = f2bf(a[3]);
    *(ushort4_t*)(wvb + i) = o;
    a = *(const float4_t*)(wfc + i);
    o[0] = f2bf(a[0]); o[1] = f2bf(a[1]); o[2] = f2bf(a[2]); o[3] = f2bf(a[3]);
    *(ushort4_t*)(wfcb + i) = o;
  }
}

// ---------------------------------------------------------------- GEMM  C = A(M,K) * B(N,K)^T
// MODE 0: Q proj  -> bf16 Qp[((h*B+b)*L + l)*64 + dk], scaled by 1/8
// MODE 1: K proj  -> bf16 Kp[((h*B+b)*L + l)*64 + dk]
// MODE 2: V proj  -> bf16 Vt[((h*B+b)*64 + dv)*L + l]   (transposed)
// MODE 3: FC      -> f32  Of[m*512 + n]
template<int MODE>
__global__ __launch_bounds__(256)
void gemm_bt(const unsigned short* __restrict__ A, const unsigned short* __restrict__ Bm,
             unsigned short* __restrict__ Ob, float* __restrict__ Of, int K) {
  __shared__ unsigned short As[128][72];
  __shared__ unsigned short Bs[64][72];
  const int tid = threadIdx.x;
  const int lane = tid & 63;
  const int wave = tid >> 6;
  const int m0 = blockIdx.x * 128;
  const int n0 = blockIdx.y * 64;
  float4_t acc[2][4] = {};

  for (int kt = 0; kt < K; kt += 64) {
#pragma unroll
    for (int i = 0; i < 4; i++) {
      int vdx = tid + i * 256;
      int r = vdx >> 3, c = (vdx & 7) * 8;
      *(short8_t*)(&As[r][c]) = *(const short8_t*)(A + (size_t)(m0 + r) * K + kt + c);
    }
#pragma unroll
    for (int i = 0; i < 2; i++) {
      int vdx = tid + i * 256;
      int r = vdx >> 3, c = (vdx & 7) * 8;
      *(short8_t*)(&Bs[r][c]) = *(const short8_t*)(Bm + (size_t)(n0 + r) * K + kt + c);
    }
    __syncthreads();
    const int wm = wave * 32;
#pragma unroll
    for (int kk = 0; kk < 2; kk++) {
      const int krow = kk * 32 + (lane >> 4) * 8;
      short8_t a[2], b[4];
#pragma unroll
      for (int mi = 0; mi < 2; mi++)
        a[mi] = *(const short8_t*)(&As[wm + mi * 16 + (lane & 15)][krow]);
#pragma unroll
      for (int ni = 0; ni < 4; ni++)
        b[ni] = *(const short8_t*)(&Bs[ni * 16 + (lane & 15)][krow]);
#pragma unroll
      for (int mi = 0; mi < 2; mi++)
#pragma unroll
        for (int ni = 0; ni < 4; ni++)
          acc[mi][ni] = __builtin_amdgcn_mfma_f32_16x16x32_bf16(a[mi], b[ni], acc[mi][ni], 0, 0, 0);
    }
    __syncthreads();
  }

#pragma unroll
  for (int mi = 0; mi < 2; mi++)
#pragma unroll
    for (int ni = 0; ni < 4; ni++)
#pragma unroll
      for (int r = 0; r < 4; r++) {
        int gm = m0 + wave * 32 + mi * 16 + (lane >> 4) * 4 + r;
        int gn = n0 + ni * 16 + (lane & 15);
        float val = acc[mi][ni][r];
        if (MODE == 0) {
          int h = gn >> 6, dk = gn & 63, bb = gm >> 11, l = gm & 2047;
          Ob[(((size_t)(h * B_ + bb)) * L_ + l) * 64 + dk] = f2bf(val * 0.125f);
        } else if (MODE == 1) {
          int h = gn >> 6, dk = gn & 63, bb = gm >> 11, l = gm & 2047;
          Ob[(((size_t)(h * B_ + bb)) * L_ + l) * 64 + dk] = f2bf(val);
        } else if (MODE == 2) {
          int h = gn >> 6, dv = gn & 63, bb = gm >> 11, l = gm & 2047;
          Ob[(((size_t)(h * B_ + bb)) * 64 + dv) * L_ + l] = f2bf(val);
        } else {
          Of[(size_t)gm * 512 + gn] = val;
        }
      }
}

// ---------------------------------------------------------------- attention
// grid: (L_/64, H_*B_). block: 256 threads = 4 waves, each wave 16 q-rows.
__global__ __launch_bounds__(256)
void attn_kernel(const unsigned short* __restrict__ Qp, const unsigned short* __restrict__ Kp,
                 const unsigned short* __restrict__ Vt, const unsigned char* __restrict__ mask,
                 const int* __restrict__ flagp, unsigned short* __restrict__ Y) {
  __shared__ unsigned short Ks[64][72];
  __shared__ unsigned short Vs[64][72];
  __shared__ unsigned short Ps[4][16][72];
  const int tid = threadIdx.x, lane = tid & 63, wave = tid >> 6;
  const int hb = blockIdx.y;
  const int h = hb >> 1, bb = hb & 1;
  const int qw = blockIdx.x * 64 + wave * 16;
  const size_t base = (size_t)hb * (L_ * 64);
  const int mscale = (*flagp) ? 1 : 4;
  const size_t mbase = (size_t)hb * L_ * L_;

  short8_t qf[2];
#pragma unroll
  for (int c = 0; c < 2; c++)
    qf[c] = *(const short8_t*)(Qp + base + (size_t)(qw + (lane & 15)) * 64 + c * 32 + (lane >> 4) * 8);

  float4_t o[4] = {};
  float mrun[4], lrun[4];
#pragma unroll
  for (int r = 0; r < 4; r++) { mrun[r] = -INFINITY; lrun[r] = 0.f; }

  for (int k0 = 0; k0 < L_; k0 += 64) {
#pragma unroll
    for (int i = 0; i < 2; i++) {
      int vdx = tid + i * 256;
      int r = vdx >> 3, c = (vdx & 7) * 8;
      *(short8_t*)(&Ks[r][c]) = *(const short8_t*)(Kp + base + (size_t)(k0 + r) * 64 + c);
      *(short8_t*)(&Vs[r][c]) = *(const short8_t*)(Vt + base + (size_t)r * L_ + k0 + c);
    }
    __syncthreads();

    // S = Q K^T  (16 q-rows x 64 kcols per wave); C-layout: col=lane&15, row=(lane>>4)*4+reg
    float4_t s[4] = {};
#pragma unroll
    for (int kk = 0; kk < 2; kk++) {
      const int krow = kk * 32 + (lane >> 4) * 8;
#pragma unroll
      for (int n = 0; n < 4; n++) {
        short8_t bf = *(const short8_t*)(&Ks[n * 16 + (lane & 15)][krow]);
        s[n] = __builtin_amdgcn_mfma_f32_16x16x32_bf16(qf[kk], bf, s[n], 0, 0, 0);
      }
    }

    // mask (ref: where(mask, -1e10, attn))
    float sv[4][4];
#pragma unroll
    for (int n = 0; n < 4; n++) {
      int kcol = k0 + n * 16 + (lane & 15);
#pragma unroll
      for (int r = 0; r < 4; r++) {
        int qq = qw + (lane >> 4) * 4 + r;
        unsigned char mk = mask[(mbase + (size_t)qq * L_ + kcol) * mscale];
        sv[n][r] = mk ? -1e10f : s[n][r];
      }
    }

    // online softmax: row stats live in the 16-lane group (l>>4 fixed)
    float tmax[4];
#pragma unroll
    for (int r = 0; r < 4; r++) {
      float t = fmaxf(fmaxf(sv[0][r], sv[1][r]), fmaxf(sv[2][r], sv[3][r]));
#pragma unroll
      for (int mm = 1; mm < 16; mm <<= 1) t = fmaxf(t, __shfl_xor(t, mm, 64));
      tmax[r] = t;
    }
    float fac[4], psum[4];
#pragma unroll
    for (int r = 0; r < 4; r++) {
      float nm = fmaxf(mrun[r], tmax[r]);
      fac[r] = __expf(mrun[r] - nm);   // exp(-inf)=0 on first tile
      mrun[r] = nm;
      psum[r] = 0.f;
    }
#pragma unroll
    for (int n = 0; n < 4; n++)
#pragma unroll
      for (int r = 0; r < 4; r++) {
        float p = __expf(sv[n][r] - mrun[r]);
        psum[r] += p;
        Ps[wave][(lane >> 4) * 4 + r][n * 16 + (lane & 15)] = f2bf(p);
      }
#pragma unroll
    for (int r = 0; r < 4; r++) {
      float t = psum[r];
#pragma unroll
      for (int mm = 1; mm < 16; mm <<= 1) t += __shfl_xor(t, mm, 64);
      lrun[r] = lrun[r] * fac[r] + t;
    }
#pragma unroll
    for (int n2 = 0; n2 < 4; n2++)
#pragma unroll
      for (int r = 0; r < 4; r++) o[n2][r] *= fac[r];

    // O += P * V  (A = P from per-wave LDS tile; B = Vt tile, rows=dv, cols=k)
#pragma unroll
    for (int kk = 0; kk < 2; kk++) {
      short8_t pa = *(const short8_t*)(&Ps[wave][lane & 15][kk * 32 + (lane >> 4) * 8]);
#pragma unroll
      for (int n2 = 0; n2 < 4; n2++) {
        short8_t vbf = *(const short8_t*)(&Vs[n2 * 16 + (lane & 15)][kk * 32 + (lane >> 4) * 8]);
        o[n2] = __builtin_amdgcn_mfma_f32_16x16x32_bf16(pa, vbf, o[n2], 0, 0, 0);
      }
    }
    __syncthreads();
  }

#pragma unroll
  for (int n2 = 0; n2 < 4; n2++)
#pragma unroll
    for (int r = 0; r < 4; r++) {
      int qq = qw + (lane >> 4) * 4 + r;
      int dv = n2 * 16 + (lane & 15);
      float val = o[n2][r] / lrun[r];
      Y[((size_t)(bb * L_ + qq)) * 512 + h * 64 + dv] = f2bf(val);
    }
}

// ---------------------------------------------------------------- bias + residual + LN (in-place on Z=d_out)
__global__ __launch_bounds__(256)
void ln_kernel(float* __restrict__ Z, const float* __restrict__ resid,
               const float* __restrict__ bfc, const float* __restrict__ gamma,
               const float* __restrict__ beta) {
  const int row = blockIdx.x;
  const int tid = threadIdx.x;
  const int lane = tid & 63, wave = tid >> 6;
  __shared__ float rs[4], rs2[4];
  float x[2];
  float s = 0.f, s2 = 0.f;
#pragma unroll
  for (int i = 0; i < 2; i++) {
    int c = tid + i * 256;
    float xv = Z[(size_t)row * 512 + c] + bfc[c] + resid[(size_t)row * 512 + c];
    x[i] = xv; s += xv; s2 += xv * xv;
  }
#pragma unroll
  for (int mm = 1; mm < 64; mm <<= 1) { s += __shfl_xor(s, mm, 64); s2 += __shfl_xor(s2, mm, 64); }
  if (lane == 0) { rs[wave] = s; rs2[wave] = s2; }
  __syncthreads();
  s = rs[0] + rs[1] + rs[2] + rs[3];
  s2 = rs2[0] + rs2[1] + rs2[2] + rs2[3];
  float mu = s * (1.f / 512.f);
  float var = s2 * (1.f / 512.f) - mu * mu;
  float inv = rsqrtf(var + 1e-5f);
#pragma unroll
  for (int i = 0; i < 2; i++) {
    int c = tid + i * 256;
    Z[(size_t)row * 512 + c] = gamma[c] * (x[i] - mu) * inv + beta[c];
  }
}

// ---------------------------------------------------------------- launch
extern "C" void kernel_launch(void* const* d_in, const int* in_sizes, int n_in,
                              void* d_out, int out_size, void* d_ws, size_t ws_size,
                              hipStream_t stream) {
  const float* q   = (const float*)d_in[0];
  const float* k   = (const float*)d_in[1];
  const float* v   = (const float*)d_in[2];
  const unsigned char* mask = (const unsigned char*)d_in[3];
  const float* Wq  = (const float*)d_in[4];
  const float* Wk  = (const float*)d_in[5];
  const float* Wv  = (const float*)d_in[6];
  const float* Wfc = (const float*)d_in[7];
  const float* bfc = (const float*)d_in[8];
  const float* gamma = (const float*)d_in[9];
  const float* beta  = (const float*)d_in[10];
  float* out = (float*)d_out;

  char* ws = (char*)d_ws;
  int* flag = (int*)ws;
  unsigned short* qb   = (unsigned short*)(ws + 256);
  unsigned short* kb   = qb + 2097152;
  unsigned short* vb   = kb + 2097152;
  unsigned short* wqb  = vb + 2097152;
  unsigned short* wkb  = wqb + 262144;
  unsigned short* wvb  = wkb + 262144;
  unsigned short* wfcb = wvb + 262144;
  unsigned short* Qp   = wfcb + 262144;
  unsigned short* Kp   = Qp + 2097152;
  unsigned short* Vt   = Kp + 2097152;
  unsigned short* Y    = Vt + 2097152;

  detect_mask<<<1, 256, 0, stream>>>(mask, flag);
  cvt_kernel<<<2048, 256, 0, stream>>>(q, k, v, Wq, Wk, Wv, Wfc,
                                       qb, kb, vb, wqb, wkb, wvb, wfcb);
  dim3 gg(32, 8);
  gemm_bt<0><<<gg, 256, 0, stream>>>(qb, wqb, Qp, nullptr, 512);
  gemm_bt<1><<<gg, 256, 0, stream>>>(kb, wkb, Kp, nullptr, 512);
  gemm_bt<2><<<gg, 256, 0, stream>>>(vb, wvb, Vt, nullptr, 512);
  attn_kernel<<<dim3(32, 16), 256, 0, stream>>>(Qp, Kp, Vt, mask, flag, Y);
  gemm_bt<3><<<gg, 256, 0, stream>>>(Y, wfcb, nullptr, out, 512);
  ln_kernel<<<4096, 256, 0, stream>>>(out, q, bfc, gamma, beta);
}